// Round 1
// baseline (206.021 us; speedup 1.0000x reference)
//
#include <hip/hip_runtime.h>
#include <hip/hip_bf16.h>

#define B_  8
#define S_  2048
#define D_  1024
#define E_  16
#define SD_ 64
#define SH_ 256
#define H_  4096
#define R_  (D_ * S_)   // 2097152 rows of w_switch (MAX_SEQ == S)

typedef __attribute__((ext_vector_type(8))) short bf16x8;
typedef __attribute__((ext_vector_type(4))) float f32x4;

static __device__ __forceinline__ short f2bf(float f) {
    union { float f; unsigned u; } v; v.f = f;
    unsigned r = v.u + 0x7fffu + ((v.u >> 16) & 1u);   // RNE to bf16
    return (short)(r >> 16);
}

// ---------------------------------------------------------------------------
// Convert w1 [16][64][256] fp32 -> MFMA B-fragment layout bf16:
// w1f[((e*2 + ks)*16 + ntile)*64 + lane][j] = w1[e][ks*32 + (lane>>4)*8 + j][ntile*16 + (lane&15)]
// ---------------------------------------------------------------------------
__global__ void convert_w1(const float* __restrict__ w1, short* __restrict__ w1f) {
    int t = blockIdx.x * 256 + threadIdx.x;           // 32768 threads
    int lane = t & 63, ntile = (t >> 6) & 15, ks = (t >> 10) & 1, e = t >> 11;
    int k0 = ks * 32 + ((lane >> 4) << 3);
    int n  = (ntile << 4) + (lane & 15);
    const float* src = w1 + ((size_t)(e * 64 + k0) * 256 + n);
    bf16x8 o;
    #pragma unroll
    for (int j = 0; j < 8; ++j) o[j] = f2bf(src[(size_t)j * 256]);
    *(bf16x8*)(w1f + ((size_t)t << 3)) = o;
}

// ---------------------------------------------------------------------------
// Convert w2 [4096][1024] fp32 -> fragment layout bf16:
// w2f[(kg*64 + ntile)*64 + lane][j] = w2[kg*32 + (lane>>4)*8 + j][ntile*16 + (lane&15)]
// ---------------------------------------------------------------------------
__global__ void convert_w2(const float* __restrict__ w2, short* __restrict__ w2f) {
    int t = blockIdx.x * 256 + threadIdx.x;           // 524288 threads
    int lane = t & 63, ntile = (t >> 6) & 63, kg = t >> 12;   // kg < 128
    int k0 = (kg << 5) + ((lane >> 4) << 3);
    int n  = (ntile << 4) + (lane & 15);
    const float* src = w2 + ((size_t)k0 * 1024 + n);
    bf16x8 o;
    #pragma unroll
    for (int j = 0; j < 8; ++j) o[j] = f2bf(src[(size_t)j * 1024]);
    *(bf16x8*)(w2f + ((size_t)t << 3)) = o;
}

// ---------------------------------------------------------------------------
// Router: logits[b][e] = sum_i x[b][i] * w_switch[i][e]
// Quad of threads per row: thread q in quad handles experts 4q..4q+3 (float4 of w).
// ---------------------------------------------------------------------------
__global__ __launch_bounds__(256) void router_kernel(const float* __restrict__ x,
                                                     const float* __restrict__ wsw,
                                                     float* __restrict__ logits) {
    __shared__ float lds[128];
    int tid = threadIdx.x;
    if (tid < 128) lds[tid] = 0.f;
    __syncthreads();

    int q = tid & 3;
    const float4* w4 = (const float4*)wsw;
    float acc[8][4];
    #pragma unroll
    for (int b = 0; b < 8; ++b)
        #pragma unroll
        for (int j = 0; j < 4; ++j) acc[b][j] = 0.f;

    for (int row = blockIdx.x * 64 + (tid >> 2); row < R_; row += gridDim.x * 64) {
        float4 w = w4[(size_t)row * 4 + q];
        #pragma unroll
        for (int b = 0; b < 8; ++b) {
            float xv = x[(size_t)b * R_ + row];
            acc[b][0] = fmaf(xv, w.x, acc[b][0]);
            acc[b][1] = fmaf(xv, w.y, acc[b][1]);
            acc[b][2] = fmaf(xv, w.z, acc[b][2]);
            acc[b][3] = fmaf(xv, w.w, acc[b][3]);
        }
    }
    #pragma unroll
    for (int b = 0; b < 8; ++b)
        #pragma unroll
        for (int j = 0; j < 4; ++j)
            atomicAdd(&lds[b * 16 + q * 4 + j], acc[b][j]);
    __syncthreads();
    if (tid < 128) atomicAdd(&logits[tid], lds[tid]);
}

// ---------------------------------------------------------------------------
// Top-2 per batch (softmax is monotone -> argmax over logits). Ties -> lower index.
// ---------------------------------------------------------------------------
__global__ void topk_kernel(const float* __restrict__ logits,
                            const float* __restrict__ bsw,
                            int* __restrict__ experts) {
    int b = threadIdx.x;
    if (b >= 8) return;
    float v[16];
    #pragma unroll
    for (int e = 0; e < 16; ++e) v[e] = logits[b * 16 + e] + bsw[e];
    int i0 = 0; float m0 = v[0];
    #pragma unroll
    for (int e = 1; e < 16; ++e) if (v[e] > m0) { m0 = v[e]; i0 = e; }
    int i1 = -1; float m1 = -3.4e38f;
    #pragma unroll
    for (int e = 0; e < 16; ++e) if (e != i0 && v[e] > m1) { m1 = v[e]; i1 = e; }
    experts[2 * b]     = i0;
    experts[2 * b + 1] = i1;
}

// ---------------------------------------------------------------------------
// Fused expert MLP: per block = (batch, 32-token tile).
// GEMM1 [32x64]@[64x256] per routed expert -> +b1 -> exact GELU -> G (LDS bf16)
// GEMM2 [32x512]@[512x1024] -> +b2 -> out
// Wave w: expert slot = w>>1, col-half = w&1 (GEMM1); col quarter = w (GEMM2).
// ---------------------------------------------------------------------------
__global__ __launch_bounds__(256, 2) void mlp_kernel(
        const float* __restrict__ x, const int* __restrict__ experts,
        const short* __restrict__ w1f, const float* __restrict__ b1,
        const short* __restrict__ w2f, const float* __restrict__ b2,
        float* __restrict__ out) {
    __shared__ short G[32][520];   // [token][512 H-cols], +8 pad (2-way bank conflicts only)

    int blk  = blockIdx.x;
    int b    = blk & 7;            // XCD-friendly: batch = blk%8
    int tok0 = (blk >> 3) << 5;
    int e0 = experts[2 * b], e1 = experts[2 * b + 1];
    int tid = threadIdx.x;
    int wid = tid >> 6, lane = tid & 63;
    int slot  = wid >> 1;
    int ex    = slot ? e1 : e0;
    int nhalf = wid & 1;
    int lrow = lane & 15, lk8 = (lane >> 4) << 3;

    // ---- GEMM1: H-slice [32 tokens x 128 cols] for (ex, nhalf) ----
    f32x4 acc1[2][8];
    #pragma unroll
    for (int m = 0; m < 2; ++m)
        #pragma unroll
        for (int n = 0; n < 8; ++n) acc1[m][n] = (f32x4){0.f, 0.f, 0.f, 0.f};

    #pragma unroll
    for (int ks = 0; ks < 2; ++ks) {
        bf16x8 a[2];
        #pragma unroll
        for (int m = 0; m < 2; ++m) {
            const float* xp = x + (((size_t)b * S_ + tok0 + m * 16 + lrow) * D_
                                   + ex * 64 + ks * 32 + lk8);
            float4 f0 = *(const float4*)xp;
            float4 f1 = *(const float4*)(xp + 4);
            bf16x8 av;
            av[0] = f2bf(f0.x); av[1] = f2bf(f0.y); av[2] = f2bf(f0.z); av[3] = f2bf(f0.w);
            av[4] = f2bf(f1.x); av[5] = f2bf(f1.y); av[6] = f2bf(f1.z); av[7] = f2bf(f1.w);
            a[m] = av;
        }
        #pragma unroll
        for (int nt = 0; nt < 8; ++nt) {
            int ntg = nhalf * 8 + nt;
            bf16x8 bf = *(const bf16x8*)(w1f + ((((size_t)(ex * 2 + ks) * 16 + ntg) * 64 + lane) << 3));
            acc1[0][nt] = __builtin_amdgcn_mfma_f32_16x16x32_bf16(a[0], bf, acc1[0][nt], 0, 0, 0);
            acc1[1][nt] = __builtin_amdgcn_mfma_f32_16x16x32_bf16(a[1], bf, acc1[1][nt], 0, 0, 0);
        }
    }

    // ---- +b1, exact GELU, write bf16 to LDS ----
    #pragma unroll
    for (int nt = 0; nt < 8; ++nt) {
        int ncol = (nhalf * 8 + nt) * 16 + lrow;      // 0..255 within expert
        float bb = b1[ex * 256 + ncol];
        #pragma unroll
        for (int m = 0; m < 2; ++m) {
            int r0 = m * 16 + ((lane >> 4) << 2);
            #pragma unroll
            for (int r = 0; r < 4; ++r) {
                float v = acc1[m][nt][r] + bb;
                v = 0.5f * v * (1.0f + erff(v * 0.70710678118f));
                G[r0 + r][slot * 256 + ncol] = f2bf(v);
            }
        }
    }
    __syncthreads();

    // ---- GEMM2: out-slice [32 tokens x 256 cols] for wave wid ----
    f32x4 acc2[2][16];
    #pragma unroll
    for (int m = 0; m < 2; ++m)
        #pragma unroll
        for (int n = 0; n < 16; ++n) acc2[m][n] = (f32x4){0.f, 0.f, 0.f, 0.f};

    for (int ks = 0; ks < 16; ++ks) {
        int e  = (ks < 8) ? e0 : e1;
        int kg = e * 8 + (ks & 7);                    // global w2f k-step
        bf16x8 a0 = *(const bf16x8*)&G[lrow][ks * 32 + lk8];
        bf16x8 a1 = *(const bf16x8*)&G[16 + lrow][ks * 32 + lk8];
        #pragma unroll
        for (int nt = 0; nt < 16; ++nt) {
            int ntg = wid * 16 + nt;
            bf16x8 bf = *(const bf16x8*)(w2f + ((((size_t)kg * 64 + ntg) * 64 + lane) << 3));
            acc2[0][nt] = __builtin_amdgcn_mfma_f32_16x16x32_bf16(a0, bf, acc2[0][nt], 0, 0, 0);
            acc2[1][nt] = __builtin_amdgcn_mfma_f32_16x16x32_bf16(a1, bf, acc2[1][nt], 0, 0, 0);
        }
    }

    // ---- epilogue: +b2, store fp32 ----
    size_t obase = ((size_t)b * S_ + tok0) * D_;
    #pragma unroll
    for (int nt = 0; nt < 16; ++nt) {
        int d = wid * 256 + nt * 16 + lrow;
        float bb = b2[d];
        #pragma unroll
        for (int m = 0; m < 2; ++m) {
            int r0 = m * 16 + ((lane >> 4) << 2);
            #pragma unroll
            for (int r = 0; r < 4; ++r)
                out[obase + (size_t)(r0 + r) * D_ + d] = acc2[m][nt][r] + bb;
        }
    }
}

// ---------------------------------------------------------------------------
extern "C" void kernel_launch(void* const* d_in, const int* in_sizes, int n_in,
                              void* d_out, int out_size, void* d_ws, size_t ws_size,
                              hipStream_t stream) {
    const float* x   = (const float*)d_in[0];
    const float* wsw = (const float*)d_in[1];
    const float* bsw = (const float*)d_in[2];
    const float* w1  = (const float*)d_in[3];
    const float* b1  = (const float*)d_in[4];
    const float* w2  = (const float*)d_in[5];
    const float* b2  = (const float*)d_in[6];
    float* out = (float*)d_out;

    float* logits = (float*)d_ws;                                   // 128 floats
    int*   experts = (int*)((char*)d_ws + 512);                     // 16 ints
    short* w1f = (short*)((char*)d_ws + 1024);                      // 512 KB
    short* w2f = (short*)((char*)d_ws + 1024 + 524288);             // 16 MB

    hipMemsetAsync(d_ws, 0, 512, stream);
    convert_w1<<<128, 256, 0, stream>>>(w1, w1f);
    convert_w2<<<2048, 256, 0, stream>>>(w2, w2f);
    router_kernel<<<2048, 256, 0, stream>>>(x, wsw, logits);
    topk_kernel<<<1, 64, 0, stream>>>(logits, bsw, experts);
    mlp_kernel<<<512, 256, 0, stream>>>(x, experts, w1f, b1, w2f, b2, out);
}

// Round 2
// 147.658 us; speedup vs baseline: 1.3953x; 1.3953x over previous
//
#include <hip/hip_runtime.h>
#include <hip/hip_bf16.h>

#define B_  8
#define S_  2048
#define D_  1024
#define E_  16
#define SD_ 64
#define SH_ 256
#define H_  4096
#define R_  (D_ * S_)   // 2097152 rows of w_switch (MAX_SEQ == S)

typedef __attribute__((ext_vector_type(8))) short bf16x8;
typedef __attribute__((ext_vector_type(4))) float f32x4;

static __device__ __forceinline__ short f2bf(float f) {
    union { float f; unsigned u; } v; v.f = f;
    unsigned r = v.u + 0x7fffu + ((v.u >> 16) & 1u);   // RNE to bf16
    return (short)(r >> 16);
}

// ---------------------------------------------------------------------------
// Convert w1 [16][64][256] fp32 -> MFMA B-fragment layout bf16
// ---------------------------------------------------------------------------
__global__ void convert_w1(const float* __restrict__ w1, short* __restrict__ w1f) {
    int t = blockIdx.x * 256 + threadIdx.x;           // 32768 threads
    int lane = t & 63, ntile = (t >> 6) & 15, ks = (t >> 10) & 1, e = t >> 11;
    int k0 = ks * 32 + ((lane >> 4) << 3);
    int n  = (ntile << 4) + (lane & 15);
    const float* src = w1 + ((size_t)(e * 64 + k0) * 256 + n);
    bf16x8 o;
    #pragma unroll
    for (int j = 0; j < 8; ++j) o[j] = f2bf(src[(size_t)j * 256]);
    *(bf16x8*)(w1f + ((size_t)t << 3)) = o;
}

// ---------------------------------------------------------------------------
// Convert w2 [4096][1024] fp32 -> fragment layout bf16
// ---------------------------------------------------------------------------
__global__ void convert_w2(const float* __restrict__ w2, short* __restrict__ w2f) {
    int t = blockIdx.x * 256 + threadIdx.x;           // 524288 threads
    int lane = t & 63, ntile = (t >> 6) & 63, kg = t >> 12;   // kg < 128
    int k0 = (kg << 5) + ((lane >> 4) << 3);
    int n  = (ntile << 4) + (lane & 15);
    const float* src = w2 + ((size_t)k0 * 1024 + n);
    bf16x8 o;
    #pragma unroll
    for (int j = 0; j < 8; ++j) o[j] = f2bf(src[(size_t)j * 1024]);
    *(bf16x8*)(w2f + ((size_t)t << 3)) = o;
}

// ---------------------------------------------------------------------------
// Router: logits[b][e] = sum_i x[b][i] * w_switch[i][e]
// Lane pair owns a row: half = lane&1 covers experts half*8..half*8+7.
// Explicit double-buffered loads; butterfly reduce; per-block partials.
// partials layout: [entry(128)][block(1024)]
// ---------------------------------------------------------------------------
__global__ __launch_bounds__(256, 4) void router_kernel(const float* __restrict__ x,
                                                        const float* __restrict__ wsw,
                                                        float* __restrict__ partials) {
    __shared__ float red[4][128];
    int tid = threadIdx.x;
    int wid = tid >> 6, lane = tid & 63;
    int half = lane & 1;                 // expert half
    int rl = lane >> 1;                  // row-in-wave 0..31
    const int NIT = 16;
    size_t base = ((size_t)blockIdx.x * 4 + wid) * (32 * NIT) + rl;

    float acc[8][8];
    #pragma unroll
    for (int b = 0; b < 8; ++b)
        #pragma unroll
        for (int e = 0; e < 8; ++e) acc[b][e] = 0.f;

    const float4* w4 = (const float4*)wsw;

    size_t row = base;
    float4 wa = w4[row * 4 + half * 2];
    float4 wb = w4[row * 4 + half * 2 + 1];
    float xv[8];
    #pragma unroll
    for (int b = 0; b < 8; ++b) xv[b] = x[(size_t)b * R_ + row];

    #pragma unroll 2
    for (int it = 0; it < NIT; ++it) {
        size_t nrow = (it < NIT - 1) ? (row + 32) : base;   // last prefetch is a dummy re-read
        float4 na = w4[nrow * 4 + half * 2];
        float4 nb = w4[nrow * 4 + half * 2 + 1];
        float nx[8];
        #pragma unroll
        for (int b = 0; b < 8; ++b) nx[b] = x[(size_t)b * R_ + nrow];

        #pragma unroll
        for (int b = 0; b < 8; ++b) {
            float xvb = xv[b];
            acc[b][0] = fmaf(xvb, wa.x, acc[b][0]);
            acc[b][1] = fmaf(xvb, wa.y, acc[b][1]);
            acc[b][2] = fmaf(xvb, wa.z, acc[b][2]);
            acc[b][3] = fmaf(xvb, wa.w, acc[b][3]);
            acc[b][4] = fmaf(xvb, wb.x, acc[b][4]);
            acc[b][5] = fmaf(xvb, wb.y, acc[b][5]);
            acc[b][6] = fmaf(xvb, wb.z, acc[b][6]);
            acc[b][7] = fmaf(xvb, wb.w, acc[b][7]);
        }
        wa = na; wb = nb;
        #pragma unroll
        for (int b = 0; b < 8; ++b) xv[b] = nx[b];
        row += 32;
    }

    // butterfly over same-half lanes (xor masks 2..32)
    #pragma unroll
    for (int b = 0; b < 8; ++b)
        #pragma unroll
        for (int e = 0; e < 8; ++e) {
            float v = acc[b][e];
            v += __shfl_xor(v, 2);
            v += __shfl_xor(v, 4);
            v += __shfl_xor(v, 8);
            v += __shfl_xor(v, 16);
            v += __shfl_xor(v, 32);
            acc[b][e] = v;
        }
    if (lane < 2) {
        #pragma unroll
        for (int b = 0; b < 8; ++b)
            #pragma unroll
            for (int e = 0; e < 8; ++e)
                red[wid][b * 16 + lane * 8 + e] = acc[b][e];
    }
    __syncthreads();
    if (tid < 128)
        partials[(size_t)tid * 1024 + blockIdx.x] =
            red[0][tid] + red[1][tid] + red[2][tid] + red[3][tid];
}

// ---------------------------------------------------------------------------
// Reduce partials -> logits, add bias, top-2 per batch.
// ---------------------------------------------------------------------------
__global__ __launch_bounds__(1024) void topk_kernel(const float* __restrict__ partials,
                                                    const float* __restrict__ bsw,
                                                    int* __restrict__ experts) {
    __shared__ float red[128][8];
    __shared__ float vlog[128];
    int tid = threadIdx.x;
    int entry = tid >> 3, sub = tid & 7;
    const float* p = partials + (size_t)entry * 1024 + sub * 128;
    float s = 0.f;
    #pragma unroll 4
    for (int i = 0; i < 128; ++i) s += p[i];
    red[entry][sub] = s;
    __syncthreads();
    if (tid < 128) {
        float t = 0.f;
        #pragma unroll
        for (int c = 0; c < 8; ++c) t += red[tid][c];
        vlog[tid] = t + bsw[tid & 15];
    }
    __syncthreads();
    if (tid < 8) {
        float v[16];
        #pragma unroll
        for (int e = 0; e < 16; ++e) v[e] = vlog[tid * 16 + e];
        int i0 = 0; float m0 = v[0];
        #pragma unroll
        for (int e = 1; e < 16; ++e) if (v[e] > m0) { m0 = v[e]; i0 = e; }
        int i1 = -1; float m1 = -3.4e38f;
        #pragma unroll
        for (int e = 0; e < 16; ++e) if (e != i0 && v[e] > m1) { m1 = v[e]; i1 = e; }
        experts[2 * tid]     = i0;
        experts[2 * tid + 1] = i1;
    }
}

// ---------------------------------------------------------------------------
// Fused expert MLP (unchanged from round 1 — passed with absmax 0.0078)
// ---------------------------------------------------------------------------
__global__ __launch_bounds__(256, 2) void mlp_kernel(
        const float* __restrict__ x, const int* __restrict__ experts,
        const short* __restrict__ w1f, const float* __restrict__ b1,
        const short* __restrict__ w2f, const float* __restrict__ b2,
        float* __restrict__ out) {
    __shared__ short G[32][520];

    int blk  = blockIdx.x;
    int b    = blk & 7;            // XCD-friendly: batch = blk%8
    int tok0 = (blk >> 3) << 5;
    int e0 = experts[2 * b], e1 = experts[2 * b + 1];
    int tid = threadIdx.x;
    int wid = tid >> 6, lane = tid & 63;
    int slot  = wid >> 1;
    int ex    = slot ? e1 : e0;
    int nhalf = wid & 1;
    int lrow = lane & 15, lk8 = (lane >> 4) << 3;

    f32x4 acc1[2][8];
    #pragma unroll
    for (int m = 0; m < 2; ++m)
        #pragma unroll
        for (int n = 0; n < 8; ++n) acc1[m][n] = (f32x4){0.f, 0.f, 0.f, 0.f};

    #pragma unroll
    for (int ks = 0; ks < 2; ++ks) {
        bf16x8 a[2];
        #pragma unroll
        for (int m = 0; m < 2; ++m) {
            const float* xp = x + (((size_t)b * S_ + tok0 + m * 16 + lrow) * D_
                                   + ex * 64 + ks * 32 + lk8);
            float4 f0 = *(const float4*)xp;
            float4 f1 = *(const float4*)(xp + 4);
            bf16x8 av;
            av[0] = f2bf(f0.x); av[1] = f2bf(f0.y); av[2] = f2bf(f0.z); av[3] = f2bf(f0.w);
            av[4] = f2bf(f1.x); av[5] = f2bf(f1.y); av[6] = f2bf(f1.z); av[7] = f2bf(f1.w);
            a[m] = av;
        }
        #pragma unroll
        for (int nt = 0; nt < 8; ++nt) {
            int ntg = nhalf * 8 + nt;
            bf16x8 bf = *(const bf16x8*)(w1f + ((((size_t)(ex * 2 + ks) * 16 + ntg) * 64 + lane) << 3));
            acc1[0][nt] = __builtin_amdgcn_mfma_f32_16x16x32_bf16(a[0], bf, acc1[0][nt], 0, 0, 0);
            acc1[1][nt] = __builtin_amdgcn_mfma_f32_16x16x32_bf16(a[1], bf, acc1[1][nt], 0, 0, 0);
        }
    }

    #pragma unroll
    for (int nt = 0; nt < 8; ++nt) {
        int ncol = (nhalf * 8 + nt) * 16 + lrow;
        float bb = b1[ex * 256 + ncol];
        #pragma unroll
        for (int m = 0; m < 2; ++m) {
            int r0 = m * 16 + ((lane >> 4) << 2);
            #pragma unroll
            for (int r = 0; r < 4; ++r) {
                float v = acc1[m][nt][r] + bb;
                v = 0.5f * v * (1.0f + erff(v * 0.70710678118f));
                G[r0 + r][slot * 256 + ncol] = f2bf(v);
            }
        }
    }
    __syncthreads();

    f32x4 acc2[2][16];
    #pragma unroll
    for (int m = 0; m < 2; ++m)
        #pragma unroll
        for (int n = 0; n < 16; ++n) acc2[m][n] = (f32x4){0.f, 0.f, 0.f, 0.f};

    for (int ks = 0; ks < 16; ++ks) {
        int e  = (ks < 8) ? e0 : e1;
        int kg = e * 8 + (ks & 7);
        bf16x8 a0 = *(const bf16x8*)&G[lrow][ks * 32 + lk8];
        bf16x8 a1 = *(const bf16x8*)&G[16 + lrow][ks * 32 + lk8];
        #pragma unroll
        for (int nt = 0; nt < 16; ++nt) {
            int ntg = wid * 16 + nt;
            bf16x8 bf = *(const bf16x8*)(w2f + ((((size_t)kg * 64 + ntg) * 64 + lane) << 3));
            acc2[0][nt] = __builtin_amdgcn_mfma_f32_16x16x32_bf16(a0, bf, acc2[0][nt], 0, 0, 0);
            acc2[1][nt] = __builtin_amdgcn_mfma_f32_16x16x32_bf16(a1, bf, acc2[1][nt], 0, 0, 0);
        }
    }

    size_t obase = ((size_t)b * S_ + tok0) * D_;
    #pragma unroll
    for (int nt = 0; nt < 16; ++nt) {
        int d = wid * 256 + nt * 16 + lrow;
        float bb = b2[d];
        #pragma unroll
        for (int m = 0; m < 2; ++m) {
            int r0 = m * 16 + ((lane >> 4) << 2);
            #pragma unroll
            for (int r = 0; r < 4; ++r)
                out[obase + (size_t)(r0 + r) * D_ + d] = acc2[m][nt][r] + bb;
        }
    }
}

// ---------------------------------------------------------------------------
extern "C" void kernel_launch(void* const* d_in, const int* in_sizes, int n_in,
                              void* d_out, int out_size, void* d_ws, size_t ws_size,
                              hipStream_t stream) {
    const float* x   = (const float*)d_in[0];
    const float* wsw = (const float*)d_in[1];
    const float* bsw = (const float*)d_in[2];
    const float* w1  = (const float*)d_in[3];
    const float* b1  = (const float*)d_in[4];
    const float* w2  = (const float*)d_in[5];
    const float* b2  = (const float*)d_in[6];
    float* out = (float*)d_out;

    int*   experts  = (int*)d_ws;                                    // 64 B
    float* partials = (float*)((char*)d_ws + 4096);                  // 128*1024*4 = 512 KB
    short* w1f = (short*)((char*)d_ws + 4096 + 524288);              // 512 KB
    short* w2f = (short*)((char*)d_ws + 4096 + 524288 + 524288);     // 8 MB

    convert_w1<<<128, 256, 0, stream>>>(w1, w1f);
    convert_w2<<<2048, 256, 0, stream>>>(w2, w2f);
    router_kernel<<<1024, 256, 0, stream>>>(x, wsw, partials);
    topk_kernel<<<1, 1024, 0, stream>>>(partials, bsw, experts);
    mlp_kernel<<<512, 256, 0, stream>>>(x, experts, w1f, b1, w2f, b2, out);
}

// Round 3
// 116.662 us; speedup vs baseline: 1.7660x; 1.2657x over previous
//
#include <hip/hip_runtime.h>
#include <hip/hip_bf16.h>

#define B_  8
#define S_  2048
#define D_  1024
#define E_  16
#define SD_ 64
#define SH_ 256
#define H_  4096
#define R_  (D_ * S_)      // 2097152 rows of w_switch (MAX_SEQ == S)
#define NBLK_ 2048         // router blocks
#define NW_   (NBLK_ * 4)  // router waves

typedef __attribute__((ext_vector_type(8))) short bf16x8;
typedef __attribute__((ext_vector_type(4))) float f32x4;

static __device__ __forceinline__ short f2bf(float f) {
    union { float f; unsigned u; } v; v.f = f;
    unsigned r = v.u + 0x7fffu + ((v.u >> 16) & 1u);   // RNE to bf16
    return (short)(r >> 16);
}

// ---------------------------------------------------------------------------
// Convert w1 [16][64][256] fp32 -> MFMA B-fragment layout bf16
// ---------------------------------------------------------------------------
__global__ void convert_w1(const float* __restrict__ w1, short* __restrict__ w1f) {
    int t = blockIdx.x * 256 + threadIdx.x;           // 32768 threads
    int lane = t & 63, ntile = (t >> 6) & 15, ks = (t >> 10) & 1, e = t >> 11;
    int k0 = ks * 32 + ((lane >> 4) << 3);
    int n  = (ntile << 4) + (lane & 15);
    const float* src = w1 + ((size_t)(e * 64 + k0) * 256 + n);
    bf16x8 o;
    #pragma unroll
    for (int j = 0; j < 8; ++j) o[j] = f2bf(src[(size_t)j * 256]);
    *(bf16x8*)(w1f + ((size_t)t << 3)) = o;
}

// ---------------------------------------------------------------------------
// Convert w2 [4096][1024] fp32 -> fragment layout bf16
// ---------------------------------------------------------------------------
__global__ void convert_w2(const float* __restrict__ w2, short* __restrict__ w2f) {
    int t = blockIdx.x * 256 + threadIdx.x;           // 524288 threads
    int lane = t & 63, ntile = (t >> 6) & 63, kg = t >> 12;   // kg < 128
    int k0 = (kg << 5) + ((lane >> 4) << 3);
    int n  = (ntile << 4) + (lane & 15);
    const float* src = w2 + ((size_t)k0 * 1024 + n);
    bf16x8 o;
    #pragma unroll
    for (int j = 0; j < 8; ++j) o[j] = f2bf(src[(size_t)j * 1024]);
    *(bf16x8*)(w2f + ((size_t)t << 3)) = o;
}

// ---------------------------------------------------------------------------
// Router: logits[b][e] = sum_i x[b][i] * w_switch[i][e]
// Block owns 1024 consecutive rows. x staged in LDS (32 KB, contiguous float4).
// Each lane owns one float4 of w per iter (expert quad q = lane&3 invariant);
// w stream is fully contiguous 1 KB/wave dwordx4, prefetched 1 iter ahead.
// acc[8][4] = 32 VGPRs -> no spills.
// partials layout: [entry(128)][block(2048)]
// ---------------------------------------------------------------------------
__global__ __launch_bounds__(256, 4) void router_kernel(const float* __restrict__ x,
                                                        const float* __restrict__ wsw,
                                                        float* __restrict__ partials) {
    __shared__ float xs[8192];                 // [batch][1024 rows], 32 KB
    int tid = threadIdx.x;
    int blk = blockIdx.x;
    size_t Rb = (size_t)blk << 10;             // first row of this block

    {   // stage x: 8 batches x 1024 rows, contiguous float4 per batch
        float4* xs4 = (float4*)xs;
        #pragma unroll
        for (int b = 0; b < 8; ++b) {
            const float4* src = (const float4*)(x + (size_t)b * R_ + Rb);
            xs4[b * 256 + tid] = src[tid];
        }
    }
    __syncthreads();

    int wid = tid >> 6, lane = tid & 63;
    int q = lane & 3;                          // expert quad (invariant)
    const float4* w4 = (const float4*)wsw;
    size_t wavebase = (((size_t)blk << 2) + wid) << 10;   // float4 index

    float acc[8][4];
    #pragma unroll
    for (int b = 0; b < 8; ++b)
        #pragma unroll
        for (int j = 0; j < 4; ++j) acc[b][j] = 0.f;

    float4 wreg = w4[wavebase + lane];
    #pragma unroll 2
    for (int it = 0; it < 16; ++it) {
        size_t nf = wavebase + lane + (size_t)((it == 15) ? 0 : (it + 1)) * 64;
        float4 wn = w4[nf];                    // prefetch next iter's w
        int rl = (wid << 8) + (it << 4) + (lane >> 2);   // local row of wreg
        #pragma unroll
        for (int b = 0; b < 8; ++b) {
            float xv = xs[(b << 10) + rl];
            acc[b][0] = fmaf(xv, wreg.x, acc[b][0]);
            acc[b][1] = fmaf(xv, wreg.y, acc[b][1]);
            acc[b][2] = fmaf(xv, wreg.z, acc[b][2]);
            acc[b][3] = fmaf(xv, wreg.w, acc[b][3]);
        }
        wreg = wn;
    }

    // reduce across the 16 lanes sharing q (xor 4,8,16,32)
    #pragma unroll
    for (int b = 0; b < 8; ++b)
        #pragma unroll
        for (int j = 0; j < 4; ++j) {
            float v = acc[b][j];
            v += __shfl_xor(v, 4);
            v += __shfl_xor(v, 8);
            v += __shfl_xor(v, 16);
            v += __shfl_xor(v, 32);
            acc[b][j] = v;
        }

    __syncthreads();                           // done reading xs; reuse as red
    float* red = xs;                           // 512 floats
    if (lane < 4) {
        #pragma unroll
        for (int b = 0; b < 8; ++b)
            #pragma unroll
            for (int j = 0; j < 4; ++j)
                red[(wid << 7) + b * 16 + q * 4 + j] = acc[b][j];
    }
    __syncthreads();
    if (tid < 128)
        partials[(size_t)tid * NBLK_ + blk] =
            red[tid] + red[128 + tid] + red[256 + tid] + red[384 + tid];
}

// ---------------------------------------------------------------------------
// Reduce partials[128][2048] -> logits[128]
// ---------------------------------------------------------------------------
__global__ __launch_bounds__(256) void reduce_kernel(const float* __restrict__ partials,
                                                     float* __restrict__ logits) {
    __shared__ float s[256];
    int e = blockIdx.x, tid = threadIdx.x;
    const float4* p4 = (const float4*)(partials + (size_t)e * NBLK_);
    float t = 0.f;
    #pragma unroll
    for (int i = 0; i < 2; ++i) {
        float4 v = p4[i * 256 + tid];
        t += v.x + v.y + v.z + v.w;
    }
    s[tid] = t;
    __syncthreads();
    #pragma unroll
    for (int off = 128; off; off >>= 1) {
        if (tid < off) s[tid] += s[tid + off];
        __syncthreads();
    }
    if (tid == 0) logits[e] = s[0];
}

// ---------------------------------------------------------------------------
// Top-2 per batch (softmax is monotone). Ties -> lower index.
// ---------------------------------------------------------------------------
__global__ void topk_kernel(const float* __restrict__ logits,
                            const float* __restrict__ bsw,
                            int* __restrict__ experts) {
    int b = threadIdx.x;
    if (b >= 8) return;
    float v[16];
    #pragma unroll
    for (int e = 0; e < 16; ++e) v[e] = logits[b * 16 + e] + bsw[e];
    int i0 = 0; float m0 = v[0];
    #pragma unroll
    for (int e = 1; e < 16; ++e) if (v[e] > m0) { m0 = v[e]; i0 = e; }
    int i1 = -1; float m1 = -3.4e38f;
    #pragma unroll
    for (int e = 0; e < 16; ++e) if (e != i0 && v[e] > m1) { m1 = v[e]; i1 = e; }
    experts[2 * b]     = i0;
    experts[2 * b + 1] = i1;
}

// ---------------------------------------------------------------------------
// Fused expert MLP (unchanged — passed with absmax 0.0078)
// ---------------------------------------------------------------------------
__global__ __launch_bounds__(256, 2) void mlp_kernel(
        const float* __restrict__ x, const int* __restrict__ experts,
        const short* __restrict__ w1f, const float* __restrict__ b1,
        const short* __restrict__ w2f, const float* __restrict__ b2,
        float* __restrict__ out) {
    __shared__ short G[32][520];

    int blk  = blockIdx.x;
    int b    = blk & 7;            // XCD-friendly: batch = blk%8
    int tok0 = (blk >> 3) << 5;
    int e0 = experts[2 * b], e1 = experts[2 * b + 1];
    int tid = threadIdx.x;
    int wid = tid >> 6, lane = tid & 63;
    int slot  = wid >> 1;
    int ex    = slot ? e1 : e0;
    int nhalf = wid & 1;
    int lrow = lane & 15, lk8 = (lane >> 4) << 3;

    f32x4 acc1[2][8];
    #pragma unroll
    for (int m = 0; m < 2; ++m)
        #pragma unroll
        for (int n = 0; n < 8; ++n) acc1[m][n] = (f32x4){0.f, 0.f, 0.f, 0.f};

    #pragma unroll
    for (int ks = 0; ks < 2; ++ks) {
        bf16x8 a[2];
        #pragma unroll
        for (int m = 0; m < 2; ++m) {
            const float* xp = x + (((size_t)b * S_ + tok0 + m * 16 + lrow) * D_
                                   + ex * 64 + ks * 32 + lk8);
            float4 f0 = *(const float4*)xp;
            float4 f1 = *(const float4*)(xp + 4);
            bf16x8 av;
            av[0] = f2bf(f0.x); av[1] = f2bf(f0.y); av[2] = f2bf(f0.z); av[3] = f2bf(f0.w);
            av[4] = f2bf(f1.x); av[5] = f2bf(f1.y); av[6] = f2bf(f1.z); av[7] = f2bf(f1.w);
            a[m] = av;
        }
        #pragma unroll
        for (int nt = 0; nt < 8; ++nt) {
            int ntg = nhalf * 8 + nt;
            bf16x8 bf = *(const bf16x8*)(w1f + ((((size_t)(ex * 2 + ks) * 16 + ntg) * 64 + lane) << 3));
            acc1[0][nt] = __builtin_amdgcn_mfma_f32_16x16x32_bf16(a[0], bf, acc1[0][nt], 0, 0, 0);
            acc1[1][nt] = __builtin_amdgcn_mfma_f32_16x16x32_bf16(a[1], bf, acc1[1][nt], 0, 0, 0);
        }
    }

    #pragma unroll
    for (int nt = 0; nt < 8; ++nt) {
        int ncol = (nhalf * 8 + nt) * 16 + lrow;
        float bb = b1[ex * 256 + ncol];
        #pragma unroll
        for (int m = 0; m < 2; ++m) {
            int r0 = m * 16 + ((lane >> 4) << 2);
            #pragma unroll
            for (int r = 0; r < 4; ++r) {
                float v = acc1[m][nt][r] + bb;
                v = 0.5f * v * (1.0f + erff(v * 0.70710678118f));
                G[r0 + r][slot * 256 + ncol] = f2bf(v);
            }
        }
    }
    __syncthreads();

    f32x4 acc2[2][16];
    #pragma unroll
    for (int m = 0; m < 2; ++m)
        #pragma unroll
        for (int n = 0; n < 16; ++n) acc2[m][n] = (f32x4){0.f, 0.f, 0.f, 0.f};

    for (int ks = 0; ks < 16; ++ks) {
        int e  = (ks < 8) ? e0 : e1;
        int kg = e * 8 + (ks & 7);
        bf16x8 a0 = *(const bf16x8*)&G[lrow][ks * 32 + lk8];
        bf16x8 a1 = *(const bf16x8*)&G[16 + lrow][ks * 32 + lk8];
        #pragma unroll
        for (int nt = 0; nt < 16; ++nt) {
            int ntg = wid * 16 + nt;
            bf16x8 bf = *(const bf16x8*)(w2f + ((((size_t)kg * 64 + ntg) * 64 + lane) << 3));
            acc2[0][nt] = __builtin_amdgcn_mfma_f32_16x16x32_bf16(a0, bf, acc2[0][nt], 0, 0, 0);
            acc2[1][nt] = __builtin_amdgcn_mfma_f32_16x16x32_bf16(a1, bf, acc2[1][nt], 0, 0, 0);
        }
    }

    size_t obase = ((size_t)b * S_ + tok0) * D_;
    #pragma unroll
    for (int nt = 0; nt < 16; ++nt) {
        int d = wid * 256 + nt * 16 + lrow;
        float bb = b2[d];
        #pragma unroll
        for (int m = 0; m < 2; ++m) {
            int r0 = m * 16 + ((lane >> 4) << 2);
            #pragma unroll
            for (int r = 0; r < 4; ++r)
                out[obase + (size_t)(r0 + r) * D_ + d] = acc2[m][nt][r] + bb;
        }
    }
}

// ---------------------------------------------------------------------------
extern "C" void kernel_launch(void* const* d_in, const int* in_sizes, int n_in,
                              void* d_out, int out_size, void* d_ws, size_t ws_size,
                              hipStream_t stream) {
    const float* x   = (const float*)d_in[0];
    const float* wsw = (const float*)d_in[1];
    const float* bsw = (const float*)d_in[2];
    const float* w1  = (const float*)d_in[3];
    const float* b1  = (const float*)d_in[4];
    const float* w2  = (const float*)d_in[5];
    const float* b2  = (const float*)d_in[6];
    float* out = (float*)d_out;

    int*   experts  = (int*)d_ws;                                    // 64 B
    float* logits   = (float*)((char*)d_ws + 512);                   // 512 B
    float* partials = (float*)((char*)d_ws + 4096);                  // 128*2048*4 = 1 MB
    short* w1f = (short*)((char*)d_ws + 4096 + 1048576);             // 512 KB
    short* w2f = (short*)((char*)d_ws + 4096 + 1048576 + 524288);    // 8.39 MB

    router_kernel<<<NBLK_, 256, 0, stream>>>(x, wsw, partials);
    reduce_kernel<<<128, 256, 0, stream>>>(partials, logits);
    topk_kernel<<<1, 64, 0, stream>>>(logits, bsw, experts);
    convert_w1<<<128, 256, 0, stream>>>(w1, w1f);
    convert_w2<<<2048, 256, 0, stream>>>(w2, w2f);
    mlp_kernel<<<512, 256, 0, stream>>>(x, experts, w1f, b1, w2f, b2, out);
}

// Round 4
// 113.418 us; speedup vs baseline: 1.8165x; 1.0286x over previous
//
#include <hip/hip_runtime.h>
#include <hip/hip_bf16.h>

#define B_  8
#define S_  2048
#define D_  1024
#define E_  16
#define SD_ 64
#define SH_ 256
#define H_  4096
#define R_  (D_ * S_)      // 2097152 rows of w_switch (MAX_SEQ == S)
#define NBLK_ 2048         // router blocks

typedef __attribute__((ext_vector_type(8))) short bf16x8;
typedef __attribute__((ext_vector_type(4))) float f32x4;

static __device__ __forceinline__ short f2bf(float f) {
    union { float f; unsigned u; } v; v.f = f;
    unsigned r = v.u + 0x7fffu + ((v.u >> 16) & 1u);   // RNE to bf16
    return (short)(r >> 16);
}

// ---------------------------------------------------------------------------
// Convert w1 [16][64][256] + w2 [4096][1024] fp32 -> MFMA B-fragment bf16.
// Blocks [0,128): w1; blocks [128,2176): w2.
// ---------------------------------------------------------------------------
__global__ void convert_w(const float* __restrict__ w1, const float* __restrict__ w2,
                          short* __restrict__ w1f, short* __restrict__ w2f) {
    int blk = blockIdx.x;
    if (blk < 128) {
        int t = blk * 256 + threadIdx.x;              // 32768 threads
        int lane = t & 63, ntile = (t >> 6) & 15, ks = (t >> 10) & 1, e = t >> 11;
        int k0 = ks * 32 + ((lane >> 4) << 3);
        int n  = (ntile << 4) + (lane & 15);
        const float* src = w1 + ((size_t)(e * 64 + k0) * 256 + n);
        bf16x8 o;
        #pragma unroll
        for (int j = 0; j < 8; ++j) o[j] = f2bf(src[(size_t)j * 256]);
        *(bf16x8*)(w1f + ((size_t)t << 3)) = o;
    } else {
        int t = (blk - 128) * 256 + threadIdx.x;      // 524288 threads
        int lane = t & 63, ntile = (t >> 6) & 63, kg = t >> 12;   // kg < 128
        int k0 = (kg << 5) + ((lane >> 4) << 3);
        int n  = (ntile << 4) + (lane & 15);
        const float* src = w2 + ((size_t)k0 * 1024 + n);
        bf16x8 o;
        #pragma unroll
        for (int j = 0; j < 8; ++j) o[j] = f2bf(src[(size_t)j * 1024]);
        *(bf16x8*)(w2f + ((size_t)t << 3)) = o;
    }
}

// ---------------------------------------------------------------------------
// Router: logits[b][e] = sum_i x[b][i] * w_switch[i][e]
// Block owns 1024 rows. x staged in 32 KB LDS. Lane owns one float4 of w
// (expert quad q = lane&3). w-stream: contiguous 1 KB/wave dwordx4,
// DEPTH-4 prefetch in named registers (no runtime-indexed array).
// partials layout: [entry(128)][block(2048)]
// ---------------------------------------------------------------------------
__global__ __launch_bounds__(256, 4) void router_kernel(const float* __restrict__ x,
                                                        const float* __restrict__ wsw,
                                                        float* __restrict__ partials) {
    __shared__ float xs[8192];                 // [batch][1024 rows], 32 KB
    int tid = threadIdx.x;
    int blk = blockIdx.x;
    size_t Rb = (size_t)blk << 10;             // first row of this block

    int wid = tid >> 6, lane = tid & 63;
    const float4* w4 = (const float4*)wsw;
    // float4 index of (row=Rb+wid*256+it*16+(lane>>2), q=lane&3) = base + it*64 + lane
    size_t wavebase = (((size_t)blk << 2) + wid) << 10;

    // depth-4 prefetch (issued before staging so latency hides under it)
    float4 wp0 = w4[wavebase + 0 * 64 + lane];
    float4 wp1 = w4[wavebase + 1 * 64 + lane];
    float4 wp2 = w4[wavebase + 2 * 64 + lane];
    float4 wp3 = w4[wavebase + 3 * 64 + lane];

    {   // stage x: 8 batches x 1024 rows, contiguous float4 per batch
        float4* xs4 = (float4*)xs;
        #pragma unroll
        for (int b = 0; b < 8; ++b) {
            const float4* src = (const float4*)(x + (size_t)b * R_ + Rb);
            xs4[b * 256 + tid] = src[tid];
        }
    }
    __syncthreads();

    float acc[8][4];
    #pragma unroll
    for (int b = 0; b < 8; ++b)
        #pragma unroll
        for (int j = 0; j < 4; ++j) acc[b][j] = 0.f;

    int rlbase = (wid << 8) + (lane >> 2);

    #define CONSUME(W, IT)                                              \
        {   int rl = rlbase + ((IT) << 4);                              \
            _Pragma("unroll")                                           \
            for (int b = 0; b < 8; ++b) {                               \
                float xv = xs[(b << 10) + rl];                          \
                acc[b][0] = fmaf(xv, (W).x, acc[b][0]);                 \
                acc[b][1] = fmaf(xv, (W).y, acc[b][1]);                 \
                acc[b][2] = fmaf(xv, (W).z, acc[b][2]);                 \
                acc[b][3] = fmaf(xv, (W).w, acc[b][3]);                 \
            }                                                           \
        }

    #pragma unroll
    for (int trip = 0; trip < 4; ++trip) {
        int base = trip * 4;
        CONSUME(wp0, base + 0); wp0 = w4[wavebase + (((base + 4) & 15) << 6) + lane];
        CONSUME(wp1, base + 1); wp1 = w4[wavebase + (((base + 5) & 15) << 6) + lane];
        CONSUME(wp2, base + 2); wp2 = w4[wavebase + (((base + 6) & 15) << 6) + lane];
        CONSUME(wp3, base + 3); wp3 = w4[wavebase + (((base + 7) & 15) << 6) + lane];
    }
    #undef CONSUME

    int q = lane & 3;
    // reduce across the 16 lanes sharing q (xor 4,8,16,32)
    #pragma unroll
    for (int b = 0; b < 8; ++b)
        #pragma unroll
        for (int j = 0; j < 4; ++j) {
            float v = acc[b][j];
            v += __shfl_xor(v, 4);
            v += __shfl_xor(v, 8);
            v += __shfl_xor(v, 16);
            v += __shfl_xor(v, 32);
            acc[b][j] = v;
        }

    __syncthreads();                           // done reading xs; reuse as red
    float* red = xs;                           // 512 floats
    if (lane < 4) {
        #pragma unroll
        for (int b = 0; b < 8; ++b)
            #pragma unroll
            for (int j = 0; j < 4; ++j)
                red[(wid << 7) + b * 16 + q * 4 + j] = acc[b][j];
    }
    __syncthreads();
    if (tid < 128)
        partials[(size_t)tid * NBLK_ + blk] =
            red[tid] + red[128 + tid] + red[256 + tid] + red[384 + tid];
}

// ---------------------------------------------------------------------------
// Reduce partials[128][2048] -> logits[128]
// ---------------------------------------------------------------------------
__global__ __launch_bounds__(256) void reduce_kernel(const float* __restrict__ partials,
                                                     float* __restrict__ logits) {
    __shared__ float s[256];
    int e = blockIdx.x, tid = threadIdx.x;
    const float4* p4 = (const float4*)(partials + (size_t)e * NBLK_);
    float t = 0.f;
    #pragma unroll
    for (int i = 0; i < 2; ++i) {
        float4 v = p4[i * 256 + tid];
        t += v.x + v.y + v.z + v.w;
    }
    s[tid] = t;
    __syncthreads();
    #pragma unroll
    for (int off = 128; off; off >>= 1) {
        if (tid < off) s[tid] += s[tid + off];
        __syncthreads();
    }
    if (tid == 0) logits[e] = s[0];
}

// ---------------------------------------------------------------------------
// Top-2 per batch (softmax is monotone). Ties -> lower index.
// ---------------------------------------------------------------------------
__global__ void topk_kernel(const float* __restrict__ logits,
                            const float* __restrict__ bsw,
                            int* __restrict__ experts) {
    int b = threadIdx.x;
    if (b >= 8) return;
    float v[16];
    #pragma unroll
    for (int e = 0; e < 16; ++e) v[e] = logits[b * 16 + e] + bsw[e];
    int i0 = 0; float m0 = v[0];
    #pragma unroll
    for (int e = 1; e < 16; ++e) if (v[e] > m0) { m0 = v[e]; i0 = e; }
    int i1 = -1; float m1 = -3.4e38f;
    #pragma unroll
    for (int e = 0; e < 16; ++e) if (e != i0 && v[e] > m1) { m1 = v[e]; i1 = e; }
    experts[2 * b]     = i0;
    experts[2 * b + 1] = i1;
}

// ---------------------------------------------------------------------------
// Fused expert MLP (unchanged — passed with absmax 0.0078)
// ---------------------------------------------------------------------------
__global__ __launch_bounds__(256, 2) void mlp_kernel(
        const float* __restrict__ x, const int* __restrict__ experts,
        const short* __restrict__ w1f, const float* __restrict__ b1,
        const short* __restrict__ w2f, const float* __restrict__ b2,
        float* __restrict__ out) {
    __shared__ short G[32][520];

    int blk  = blockIdx.x;
    int b    = blk & 7;            // XCD-friendly: batch = blk%8
    int tok0 = (blk >> 3) << 5;
    int e0 = experts[2 * b], e1 = experts[2 * b + 1];
    int tid = threadIdx.x;
    int wid = tid >> 6, lane = tid & 63;
    int slot  = wid >> 1;
    int ex    = slot ? e1 : e0;
    int nhalf = wid & 1;
    int lrow = lane & 15, lk8 = (lane >> 4) << 3;

    f32x4 acc1[2][8];
    #pragma unroll
    for (int m = 0; m < 2; ++m)
        #pragma unroll
        for (int n = 0; n < 8; ++n) acc1[m][n] = (f32x4){0.f, 0.f, 0.f, 0.f};

    #pragma unroll
    for (int ks = 0; ks < 2; ++ks) {
        bf16x8 a[2];
        #pragma unroll
        for (int m = 0; m < 2; ++m) {
            const float* xp = x + (((size_t)b * S_ + tok0 + m * 16 + lrow) * D_
                                   + ex * 64 + ks * 32 + lk8);
            float4 f0 = *(const float4*)xp;
            float4 f1 = *(const float4*)(xp + 4);
            bf16x8 av;
            av[0] = f2bf(f0.x); av[1] = f2bf(f0.y); av[2] = f2bf(f0.z); av[3] = f2bf(f0.w);
            av[4] = f2bf(f1.x); av[5] = f2bf(f1.y); av[6] = f2bf(f1.z); av[7] = f2bf(f1.w);
            a[m] = av;
        }
        #pragma unroll
        for (int nt = 0; nt < 8; ++nt) {
            int ntg = nhalf * 8 + nt;
            bf16x8 bf = *(const bf16x8*)(w1f + ((((size_t)(ex * 2 + ks) * 16 + ntg) * 64 + lane) << 3));
            acc1[0][nt] = __builtin_amdgcn_mfma_f32_16x16x32_bf16(a[0], bf, acc1[0][nt], 0, 0, 0);
            acc1[1][nt] = __builtin_amdgcn_mfma_f32_16x16x32_bf16(a[1], bf, acc1[1][nt], 0, 0, 0);
        }
    }

    #pragma unroll
    for (int nt = 0; nt < 8; ++nt) {
        int ncol = (nhalf * 8 + nt) * 16 + lrow;
        float bb = b1[ex * 256 + ncol];
        #pragma unroll
        for (int m = 0; m < 2; ++m) {
            int r0 = m * 16 + ((lane >> 4) << 2);
            #pragma unroll
            for (int r = 0; r < 4; ++r) {
                float v = acc1[m][nt][r] + bb;
                v = 0.5f * v * (1.0f + erff(v * 0.70710678118f));
                G[r0 + r][slot * 256 + ncol] = f2bf(v);
            }
        }
    }
    __syncthreads();

    f32x4 acc2[2][16];
    #pragma unroll
    for (int m = 0; m < 2; ++m)
        #pragma unroll
        for (int n = 0; n < 16; ++n) acc2[m][n] = (f32x4){0.f, 0.f, 0.f, 0.f};

    for (int ks = 0; ks < 16; ++ks) {
        int e  = (ks < 8) ? e0 : e1;
        int kg = e * 8 + (ks & 7);
        bf16x8 a0 = *(const bf16x8*)&G[lrow][ks * 32 + lk8];
        bf16x8 a1 = *(const bf16x8*)&G[16 + lrow][ks * 32 + lk8];
        #pragma unroll
        for (int nt = 0; nt < 16; ++nt) {
            int ntg = wid * 16 + nt;
            bf16x8 bf = *(const bf16x8*)(w2f + ((((size_t)kg * 64 + ntg) * 64 + lane) << 3));
            acc2[0][nt] = __builtin_amdgcn_mfma_f32_16x16x32_bf16(a0, bf, acc2[0][nt], 0, 0, 0);
            acc2[1][nt] = __builtin_amdgcn_mfma_f32_16x16x32_bf16(a1, bf, acc2[1][nt], 0, 0, 0);
        }
    }

    size_t obase = ((size_t)b * S_ + tok0) * D_;
    #pragma unroll
    for (int nt = 0; nt < 16; ++nt) {
        int d = wid * 256 + nt * 16 + lrow;
        float bb = b2[d];
        #pragma unroll
        for (int m = 0; m < 2; ++m) {
            int r0 = m * 16 + ((lane >> 4) << 2);
            #pragma unroll
            for (int r = 0; r < 4; ++r)
                out[obase + (size_t)(r0 + r) * D_ + d] = acc2[m][nt][r] + bb;
        }
    }
}

// ---------------------------------------------------------------------------
extern "C" void kernel_launch(void* const* d_in, const int* in_sizes, int n_in,
                              void* d_out, int out_size, void* d_ws, size_t ws_size,
                              hipStream_t stream) {
    const float* x   = (const float*)d_in[0];
    const float* wsw = (const float*)d_in[1];
    const float* bsw = (const float*)d_in[2];
    const float* w1  = (const float*)d_in[3];
    const float* b1  = (const float*)d_in[4];
    const float* w2  = (const float*)d_in[5];
    const float* b2  = (const float*)d_in[6];
    float* out = (float*)d_out;

    int*   experts  = (int*)d_ws;                                    // 64 B
    float* logits   = (float*)((char*)d_ws + 512);                   // 512 B
    float* partials = (float*)((char*)d_ws + 4096);                  // 128*2048*4 = 1 MB
    short* w1f = (short*)((char*)d_ws + 4096 + 1048576);             // 512 KB
    short* w2f = (short*)((char*)d_ws + 4096 + 1048576 + 524288);    // 8.39 MB

    router_kernel<<<NBLK_, 256, 0, stream>>>(x, wsw, partials);
    reduce_kernel<<<128, 256, 0, stream>>>(partials, logits);
    topk_kernel<<<1, 64, 0, stream>>>(logits, bsw, experts);
    convert_w<<<2176, 256, 0, stream>>>(w1, w2, w1f, w2f);
    mlp_kernel<<<512, 256, 0, stream>>>(x, experts, w1f, b1, w2f, b2, out);
}